// Round 6
// baseline (340.539 us; speedup 1.0000x reference)
//
#include <hip/hip_runtime.h>

// Problem constants
constexpr int B  = 64;
constexpr int U  = 512;
constexpr int AE = 1024;
constexpr int UE = 256;
constexpr int A  = 256;     // head size
constexpr int KQ = AE + UE; // 1280

typedef _Float16 f16x8 __attribute__((ext_vector_type(8)));
typedef _Float16 f16x4 __attribute__((ext_vector_type(4)));
typedef float    f32x4 __attribute__((ext_vector_type(4)));

// ---------------------------------------------------------------------------
// K0: cast+transpose weights to fp16 [N][K] so B-frags are k-contiguous
// ---------------------------------------------------------------------------
__global__ void prep(const float* __restrict__ Wq, const float* __restrict__ Wk,
                     _Float16* __restrict__ WqT, _Float16* __restrict__ WkT) {
    int idx = blockIdx.x * 256 + threadIdx.x;
    if (idx < KQ * A) {
        int k = idx >> 8, n = idx & 255;
        WqT[(size_t)n * KQ + k] = (_Float16)Wq[idx];
    } else {
        int j = idx - KQ * A;
        if (j < A * A) {
            int k = j >> 8, n = j & 255;
            WkT[(size_t)n * A + k] = (_Float16)Wk[j];
        }
    }
}

// ---------------------------------------------------------------------------
// K1/K2: C = concat(A1|A2)[m][k]*BT[n][k]+bias, fp16 out, permuted layout
// [bb=row>>9][c5=col>>5][u=row&511][col&31].
// BM=128 x BN=256 (A read once), BK=64, 512 thr / 8 waves, wave tile 64x64.
// Single-barrier DOUBLE-BUFFERED K-loop: ds_write regs->buf[k&1]; barrier
// (vmcnt already drained by the write's own wait -> free); issue loads k+1;
// mfma buf[k&1]. Memory pipe streams continuously at 1 block/CU.
// Epilogue: C staged through LDS (overlay) -> 16B/lane contiguous stores.
// Swizzle: 16B-chunk index ^= (row & 7) -> conflict-free frag reads.
// KTOT/SPLIT are template params => distinct kernel symbols for profiling.
// ---------------------------------------------------------------------------
template<int KTOT, int SPLIT>
__global__ __launch_bounds__(512, 2) void gemm(
    const float* __restrict__ A1, int s1,
    const float* __restrict__ A2, int s2,
    const _Float16* __restrict__ BT,   // [256][KTOT] fp16
    const float* __restrict__ bias,    // [256]
    _Float16* __restrict__ Out)        // permuted
{
    __shared__ __align__(16) char smem[98304];            // 96 KB
    _Float16 (*Ab)[128][64] = (_Float16(*)[128][64])smem;           // 2 x 16 KB
    _Float16 (*Bb)[256][64] = (_Float16(*)[256][64])(smem + 32768); // 2 x 32 KB
    _Float16 (*Cl)[264]     = (_Float16(*)[264])smem;               // overlay, 67.6 KB

    const int t    = threadIdx.x;
    const int lane = t & 63;
    const int w    = t >> 6;                // 0..7
    const int lm   = lane & 15;
    const int mbase = blockIdx.x * 128;
    const int wm = (w & 1) * 64;
    const int wn = (w >> 1) * 64;

    f32x4 acc[4][4] = {};

    // A staging: thread -> row (0..127), 16-float k-seg (0..3)
    const int arow = t >> 2, aseg = t & 3;
    const size_t ga = mbase + arow;
    // B staging: thread -> row (0..255), 32-f16 k-half (0..1)
    const int brow = t >> 1, bseg = t & 1;

    float4 aR[4];
    f16x8  bR[4];
    auto loadA = [&](int k0) {
        int kg = k0 + aseg * 16;            // SPLIT is a multiple of 16
        const float* s = (kg < SPLIT) ? (A1 + ga * (size_t)s1 + kg)
                                      : (A2 + ga * (size_t)s2 + (kg - SPLIT));
        aR[0] = ((const float4*)s)[0]; aR[1] = ((const float4*)s)[1];
        aR[2] = ((const float4*)s)[2]; aR[3] = ((const float4*)s)[3];
    };
    auto loadB = [&](int k0) {
        const _Float16* s = BT + (size_t)brow * KTOT + k0 + bseg * 32;
        bR[0] = ((const f16x8*)s)[0]; bR[1] = ((const f16x8*)s)[1];
        bR[2] = ((const f16x8*)s)[2]; bR[3] = ((const f16x8*)s)[3];
    };

    loadA(0); loadB(0);

    constexpr int nk = KTOT / 64;
    for (int kb = 0; kb < nk; kb++) {
        const int bi = kb & 1;
        // publish staged regs (compiler inserts the vmcnt wait here)
        #pragma unroll
        for (int j = 0; j < 2; j++) {
            const float4 x = aR[2 * j], y = aR[2 * j + 1];
            f16x8 hv;
            hv[0] = (_Float16)x.x; hv[1] = (_Float16)x.y;
            hv[2] = (_Float16)x.z; hv[3] = (_Float16)x.w;
            hv[4] = (_Float16)y.x; hv[5] = (_Float16)y.y;
            hv[6] = (_Float16)y.z; hv[7] = (_Float16)y.w;
            int c = aseg * 2 + j;
            *(f16x8*)(&Ab[bi][arow][(c ^ (arow & 7)) * 8]) = hv;
        }
        #pragma unroll
        for (int j = 0; j < 4; j++) {
            int c = bseg * 4 + j;
            *(f16x8*)(&Bb[bi][brow][(c ^ (brow & 7)) * 8]) = bR[j];
        }
        __syncthreads();     // vmcnt already 0 here -> cheap drain
        if (kb + 1 < nk) { loadA((kb + 1) * 64); loadB((kb + 1) * 64); }  // stream next tile
        #pragma unroll
        for (int p = 0; p < 2; p++) {
            f16x8 af[4], bf[4];
            #pragma unroll
            for (int mt = 0; mt < 4; mt++) {
                int r = wm + mt * 16 + lm;
                af[mt] = *(const f16x8*)(&Ab[bi][r][((p * 4 + (lane >> 4)) ^ (r & 7)) * 8]);
            }
            #pragma unroll
            for (int nt = 0; nt < 4; nt++) {
                int r = wn + nt * 16 + lm;
                bf[nt] = *(const f16x8*)(&Bb[bi][r][((p * 4 + (lane >> 4)) ^ (r & 7)) * 8]);
            }
            #pragma unroll
            for (int mt = 0; mt < 4; mt++)
                #pragma unroll
                for (int nt = 0; nt < 4; nt++)
                    acc[mt][nt] = __builtin_amdgcn_mfma_f32_16x16x32_f16(
                        af[mt], bf[nt], acc[mt][nt], 0, 0, 0);
        }
    }

    // ---- epilogue: stage C in LDS, then fully-coalesced 16B/lane stores
    __syncthreads();                        // all mfma LDS reads done (overlay)
    const int rsub = (lane >> 4) * 4;
    #pragma unroll
    for (int nt = 0; nt < 4; nt++) {
        const int col = wn + nt * 16 + lm;
        const float bv = bias[col];
        #pragma unroll
        for (int mt = 0; mt < 4; mt++)
            #pragma unroll
            for (int r = 0; r < 4; r++)
                Cl[wm + mt * 16 + rsub + r][col] = (_Float16)(acc[mt][nt][r] + bv);
    }
    __syncthreads();
    const int bb = mbase >> 9, u0 = mbase & 511;
    const int uu = t >> 2, q = t & 3;
    #pragma unroll
    for (int c5 = 0; c5 < 8; c5++) {
        // row stride 264 f16 = 528 B -> 8B-aligned: two b64 reads
        f16x4 v0 = *(const f16x4*)(&Cl[uu][c5 * 32 + q * 8]);
        f16x4 v1 = *(const f16x4*)(&Cl[uu][c5 * 32 + q * 8 + 4]);
        f16x8 v;
        v[0]=v0[0]; v[1]=v0[1]; v[2]=v0[2]; v[3]=v0[3];
        v[4]=v1[0]; v[5]=v1[1]; v[6]=v1[2]; v[7]=v1[3];
        *(f16x8*)(Out + (((size_t)bb * 8 + c5) * 512 + u0 + uu) * 32 + q * 8) = v;
    }
}

// ---------------------------------------------------------------------------
// K3: block = (batch, 64 q-rows), 512 thr / 8 waves; wave = 32 rows x 128
// cols. S = Qh Kh^T / 16, multiplicative mask, register softmax + LDS
// cross-wave combine. K chunks single-barrier DOUBLE-BUFFERED like gemm.
// Epilogue: per-wave LDS restage -> 512B-contiguous half-wave stores.
// ---------------------------------------------------------------------------
__global__ __launch_bounds__(512, 2) void attn(
    const _Float16* __restrict__ Qh, const _Float16* __restrict__ Kh,
    const int* __restrict__ nr_own_units, const int* __restrict__ nr_units_enemy,
    const int* __restrict__ nr_own_flags, float* __restrict__ Out)
{
    __shared__ __align__(16) char smem[98304];            // 96 KB
    _Float16 (*Ql)[64][32]  = (_Float16(*)[64][32])smem;            // 8 x 4 KB
    _Float16 (*Kl)[512][32] = (_Float16(*)[512][32])(smem + 32768); // 2 x 32 KB
    __shared__ float red[64][4];

    const int t    = threadIdx.x;
    const int lane = t & 63;
    const int w    = t >> 6;                 // 0..7
    const int lm   = lane & 15;
    const int b    = blockIdx.y;
    const int qbase = blockIdx.x * 64;

    const int wm = (w & 1) * 32;             // wave row base (0/32)
    const int wn = (w >> 1) * 128;           // wave col base

    const int nf = nr_own_flags[b];
    const int nu = nr_own_units[b];
    const int ne = nr_units_enemy[b];

    // ---- stage Q once (swizzle: chunk ^= row&3)
    {
        f16x8 qreg[4];
        #pragma unroll
        for (int j = 0; j < 4; j++) {
            int s = j * 512 + t;
            int p = s >> 8, row = (s & 255) >> 2, cq = s & 3;
            qreg[j] = *(const f16x8*)(Qh + (((size_t)b * 8 + p) * 512 + qbase + row) * 32 + cq * 8);
        }
        #pragma unroll
        for (int j = 0; j < 4; j++) {
            int s = j * 512 + t;
            int p = s >> 8, row = (s & 255) >> 2, cq = s & 3;
            *(f16x8*)(&Ql[p][row][(cq ^ (row & 3)) * 8]) = qreg[j];
        }
    }

    // ---- K chunk staging: thread t -> row t (64 B contiguous)
    const _Float16* Kb = Kh + (size_t)b * 8 * 512 * 32;
    f16x8 kreg[4];
    auto loadK = [&](int c) {
        const _Float16* s = Kb + ((size_t)c * 512 + t) * 32;
        kreg[0] = ((const f16x8*)s)[0]; kreg[1] = ((const f16x8*)s)[1];
        kreg[2] = ((const f16x8*)s)[2]; kreg[3] = ((const f16x8*)s)[3];
    };
    loadK(0);

    f32x4 acc[2][8] = {};
    for (int c = 0; c < 8; c++) {
        const int bi = c & 1;
        #pragma unroll
        for (int j = 0; j < 4; j++)
            *(f16x8*)(&Kl[bi][t][(j ^ (t & 3)) * 8]) = kreg[j];
        __syncthreads();     // also publishes Ql on c==0
        if (c < 7) loadK(c + 1);
        f16x8 af[2], bf[8];
        #pragma unroll
        for (int mt = 0; mt < 2; mt++) {
            int r = wm + mt * 16 + lm;
            af[mt] = *(const f16x8*)(&Ql[c][r][((lane >> 4) ^ (r & 3)) * 8]);
        }
        #pragma unroll
        for (int nt = 0; nt < 8; nt++) {
            int r = wn + nt * 16 + lm;
            bf[nt] = *(const f16x8*)(&Kl[bi][r][((lane >> 4) ^ (r & 3)) * 8]);
        }
        #pragma unroll
        for (int mt = 0; mt < 2; mt++)
            #pragma unroll
            for (int nt = 0; nt < 8; nt++)
                acc[mt][nt] = __builtin_amdgcn_mfma_f32_16x16x32_f16(
                    af[mt], bf[nt], acc[mt][nt], 0, 0, 0);
    }

    // ---- mask + scale in registers
    const int rsub = (lane >> 4) * 4;
    #pragma unroll
    for (int mt = 0; mt < 2; mt++)
        #pragma unroll
        for (int nt = 0; nt < 8; nt++)
            #pragma unroll
            for (int r = 0; r < 4; r++) {
                int uq = qbase + wm + mt * 16 + rsub + r;
                int col = wn + nt * 16 + lm;
                bool ok = (col < ne) && (uq >= nf) && (uq < nu);
                acc[mt][nt][r] = acc[mt][nt][r] * 0.0625f * (ok ? 1.0f : 1e-9f);
            }

    // ---- row max
    float mx[2][4];
    #pragma unroll
    for (int mt = 0; mt < 2; mt++)
        #pragma unroll
        for (int r = 0; r < 4; r++) {
            float m = acc[mt][0][r];
            #pragma unroll
            for (int nt = 1; nt < 8; nt++) m = fmaxf(m, acc[mt][nt][r]);
            #pragma unroll
            for (int off = 1; off <= 8; off <<= 1) m = fmaxf(m, __shfl_xor(m, off));
            mx[mt][r] = m;
        }
    if (lm == 0)
        #pragma unroll
        for (int mt = 0; mt < 2; mt++)
            #pragma unroll
            for (int r = 0; r < 4; r++)
                red[wm + mt * 16 + rsub + r][w >> 1] = mx[mt][r];
    __syncthreads();
    #pragma unroll
    for (int mt = 0; mt < 2; mt++)
        #pragma unroll
        for (int r = 0; r < 4; r++) {
            f32x4 v = *(const f32x4*)(&red[wm + mt * 16 + rsub + r][0]);
            mx[mt][r] = fmaxf(fmaxf(v[0], v[1]), fmaxf(v[2], v[3]));
        }
    __syncthreads();

    // ---- exp + row sum
    float sm[2][4];
    #pragma unroll
    for (int mt = 0; mt < 2; mt++)
        #pragma unroll
        for (int r = 0; r < 4; r++) {
            float s = 0.f;
            #pragma unroll
            for (int nt = 0; nt < 8; nt++) {
                float e = __expf(acc[mt][nt][r] - mx[mt][r]);
                acc[mt][nt][r] = e;
                s += e;
            }
            #pragma unroll
            for (int off = 1; off <= 8; off <<= 1) s += __shfl_xor(s, off);
            sm[mt][r] = s;
        }
    if (lm == 0)
        #pragma unroll
        for (int mt = 0; mt < 2; mt++)
            #pragma unroll
            for (int r = 0; r < 4; r++)
                red[wm + mt * 16 + rsub + r][w >> 1] = sm[mt][r];
    __syncthreads();   // after this, all mfma/LDS reads done -> S may overlay

    float inv[2][4];
    #pragma unroll
    for (int mt = 0; mt < 2; mt++)
        #pragma unroll
        for (int r = 0; r < 4; r++) {
            f32x4 v = *(const f32x4*)(&red[wm + mt * 16 + rsub + r][0]);
            inv[mt][r] = 1.0f / (v[0] + v[1] + v[2] + v[3]);
        }
    __syncthreads();   // red reads done; Ql/Kl region free for overlay

    // ---- per-wave restage: 16 rows x 128 cols fp32 (stride 132), 2 rounds
    float* Sw = (float*)(smem + w * 8448);   // 16*132*4 = 8448 B per wave
    #pragma unroll
    for (int mt = 0; mt < 2; mt++) {
        #pragma unroll
        for (int nt = 0; nt < 8; nt++)
            #pragma unroll
            for (int r = 0; r < 4; r++)
                Sw[(rsub + r) * 132 + nt * 16 + lm] = acc[mt][nt][r] * inv[mt][r];
        // wave-local: no barrier needed between write and read
        const int srow = lane >> 5;          // 0/1
        const int scol = (lane & 31) * 4;
        #pragma unroll
        for (int pass = 0; pass < 8; pass++) {
            int row = pass * 2 + srow;
            float2 a0 = *(const float2*)(&Sw[row * 132 + scol]);
            float2 a1 = *(const float2*)(&Sw[row * 132 + scol + 2]);
            float4 v; v.x = a0.x; v.y = a0.y; v.z = a1.x; v.w = a1.y;
            *(float4*)(Out + ((size_t)b * 512 + qbase + wm + mt * 16 + row) * 512
                           + wn + scol) = v;
        }
        // next round reuses the same wave-local region; wave-local ordering ok
    }
}

// ---------------------------------------------------------------------------
extern "C" void kernel_launch(void* const* d_in, const int* in_sizes, int n_in,
                              void* d_out, int out_size, void* d_ws, size_t ws_size,
                              hipStream_t stream) {
    const float* ar    = (const float*)d_in[0];   // [B,U,AE]
    const float* own   = (const float*)d_in[1];   // [B,U,UE]
    const float* enemy = (const float*)d_in[2];   // [B,U,UE]
    const int*   n_own   = (const int*)d_in[3];
    const int*   n_enemy = (const int*)d_in[4];
    const int*   n_flags = (const int*)d_in[5];
    const float* Wq = (const float*)d_in[6];
    const float* bq = (const float*)d_in[7];
    const float* Wk = (const float*)d_in[8];
    const float* bk = (const float*)d_in[9];
    float* out = (float*)d_out;

    char* ws = (char*)d_ws;
    _Float16* WqT = (_Float16*)(ws);                       // 256x1280 fp16
    _Float16* WkT = (_Float16*)(ws + 655360);              // 256x256  fp16
    _Float16* Qh  = (_Float16*)(ws + 786432);              // [64][8][512][32] f16
    _Float16* Kh  = (_Float16*)(ws + 786432 + 16777216);   // [64][8][512][32] f16

    prep<<<dim3((KQ * A + A * A) / 256), dim3(256), 0, stream>>>(Wq, Wk, WqT, WkT);

    // Q = concat(ar, own) @ Wq + bq   (M=32768, K=1280) — 256 blocks, 1/CU
    gemm<KQ, AE><<<dim3(256), dim3(512), 0, stream>>>(ar, AE, own, UE, WqT, bq, Qh);
    // K = enemy @ Wk + bk             (M=32768, K=256)
    gemm<A, 0><<<dim3(256), dim3(512), 0, stream>>>(enemy, UE, enemy, UE, WkT, bk, Kh);

    attn<<<dim3(8, B), dim3(512), 0, stream>>>(Qh, Kh, n_own, n_enemy, n_flags, out);
}